// Round 13
// baseline (186.798 us; speedup 1.0000x reference)
//
#include <hip/hip_runtime.h>
#include <hip/hip_bf16.h>

typedef __attribute__((ext_vector_type(8))) short s16x8;
typedef __attribute__((ext_vector_type(4))) short s16x4;
typedef __attribute__((ext_vector_type(4))) float f32x4;

#define SEQ 8192

__device__ __forceinline__ float bf2f(short s){
  union { unsigned u; float f; } c; c.u = ((unsigned)(unsigned short)s) << 16; return c.f;
}
__device__ __forceinline__ short f2bf(float f){
  __hip_bfloat16 h = __float2bfloat16(f);
  short s; __builtin_memcpy(&s, &h, 2); return s;
}

// ---------------- transpose tile body (fp32 (R,C) -> bf16 (C,R)) ----------------
__device__ __forceinline__ void transpose_body(const float* __restrict__ in, __hip_bfloat16* __restrict__ out,
                                               int R, int C, int bx, int by){
  __shared__ float tile[32][33];
  int c0 = bx*32, r0 = by*32;
  int tx = threadIdx.x & 31, ty = threadIdx.x >> 5;
  #pragma unroll
  for (int i = ty; i < 32; i += 8) tile[i][tx] = in[(size_t)(r0+i)*C + c0 + tx];
  __syncthreads();
  #pragma unroll
  for (int i = ty; i < 32; i += 8) out[(size_t)(c0+i)*R + r0 + tx] = __float2bfloat16(tile[tx][i]);
}

// ---------------- fused prep: cvt_x | rotary table | transposes ----------------
__global__ __launch_bounds__(256) void prep(
    const float* __restrict__ x, __hip_bfloat16* __restrict__ xb, unsigned* __restrict__ tab,
    const float* __restrict__ wqkv, __hip_bfloat16* __restrict__ wqkvT,
    const float* __restrict__ wout, __hip_bfloat16* __restrict__ woutT)
{
  int b = blockIdx.x;
  if (b < 16384){
    int i = b*256 + threadIdx.x;
    float4 v = reinterpret_cast<const float4*>(x)[i];
    s16x4 o = { f2bf(v.x), f2bf(v.y), f2bf(v.z), f2bf(v.w) };
    reinterpret_cast<s16x4*>(xb)[i] = o;
  } else if (b < 18432){
    int idx = (b - 16384)*256 + threadIdx.x;   // n*64 + d
    int n = idx >> 6, d = idx & 63;
    float c, s;
    if (d < 32){
      float ex = -(float)(d & ~1) / 32.0f;
      float invf = __expf(ex * 9.210340371976184f);   // 10000^ex
      float f = (float)n * invf;
      __sincosf(f, &s, &c);
      s = (d & 1) ? s : -s;
    } else { c = 1.f; s = 0.f; }
    tab[idx] = (unsigned)(unsigned short)f2bf(c) | ((unsigned)(unsigned short)f2bf(s) << 16);
  } else if (b < 19200){
    int id = b - 18432;                        // 48 x 16 tiles
    transpose_body(wqkv, wqkvT, 512, 1536, id % 48, id / 48);
  } else {
    int id = b - 19200;                        // 16 x 16 tiles
    transpose_body(wout, woutT, 512, 512, id % 16, id / 16);
  }
}

// ================= 128x256 GEMM, K=512 constexpr (full unroll), BK=32, 3 LDS bufs, 2 blocks/CU =================
// Identical schedule/layout to R9/R11 (best). K made compile-time so all ds_read/staging addresses
// fold to per-thread base + immediate offsets (kills in-loop VALU addr math).
// NOTE: 2 blocks/CU is the occupancy ceiling — launch_bounds(512,6) spills acc (R10: 1.37GB scratch).
template<int MODE>
__global__ __launch_bounds__(512, 4) void gemm128(
    const __hip_bfloat16* __restrict__ A, const __hip_bfloat16* __restrict__ BT,
    int M, int Nn,
    __hip_bfloat16* __restrict__ oQ, __hip_bfloat16* __restrict__ oK, __hip_bfloat16* __restrict__ oV,
    float* __restrict__ oF, const float* __restrict__ bias)
{
  constexpr int K = 512;
  constexpr int NKT = K >> 5;          // 16 K-tiles, BK=32
  __shared__ __align__(16) char lds[73728];   // 3 x (A 128x32 + B 256x32) bf16 = 3 x 24KB
  const int t = threadIdx.x;
  const int lane = t & 63, wid = t >> 6;
  const int lr = lane & 15, lg = lane >> 4;
  const int wm   = (wid >> 2) * 64;    // 0,64
  const int wn64 = (wid & 3) * 64;     // 0..192

  // XCD-bijective swizzle, bn-fastest: each XCD owns a contiguous M-band (A-band ~4MB = its L2)
  int nwg = gridDim.x, per = nwg >> 3, wg = blockIdx.x;
  int swz = (wg & 7) * per + (wg >> 3);
  int nblk = Nn >> 8;                  // 256-col tiles
  int bm = (swz / nblk) << 7;          // 128-row tiles
  int bn = (swz % nblk) << 8;

  // staging: 1536 granules of 16B per tile; 3/thread. Source chunk pre-swizzled with
  // s(row) = (row>>1)&3 (involution with read XOR; bank = 16*(r&1)+4*chunk -> 2-way max)
  const __hip_bfloat16* spp[3];
  int dofs[3];
  #pragma unroll
  for (int i = 0; i < 3; ++i){
    int g = (i == 0) ? t : (t + (i-1)*512);
    int row = g >> 2, ch = g & 3;
    int sch = ch ^ ((row >> 1) & 3);
    spp[i] = (i == 0 ? A + (size_t)(bm + row)*K : BT + (size_t)(bn + row)*K) + sch*8;
    dofs[i] = ((i == 0) ? 0 : 8192) + g*16;
  }
  #define STG(i, kt2, bufo) __builtin_amdgcn_global_load_lds( \
      (const __attribute__((address_space(1))) void*)(spp[i] + (size_t)(kt2)*32), \
      (__attribute__((address_space(3))) void*)(lds + (bufo) + dofs[i]), 16, 0, 0)

  // prologue: stage tiles 0,1 into bufs 0,1
  STG(0, 0, 0); STG(1, 0, 0); STG(2, 0, 0);
  STG(0, 1, 24576); STG(1, 1, 24576); STG(2, 1, 24576);

  f32x4 acc[4][4] = {};
  #define SWR(r) ((((r) >> 1) & 3) << 4)

  // per-thread loop-invariant LDS byte offsets (buffer-base added as compile-time constant per kt)
  int aoff[4], boff[4];
  #pragma unroll
  for (int f = 0; f < 4; ++f){
    int ra = wm + f*16 + lr;
    aoff[f] = (ra << 6) + ((lg << 4) ^ SWR(ra));
    int rb2 = wn64 + f*16 + lr;
    boff[f] = 8192 + (rb2 << 6) + ((lg << 4) ^ SWR(rb2));
  }

  #pragma unroll
  for (int kt = 0; kt < NKT; ++kt){
    const int rOff = (kt % 3) * 24576;
    const int sOff = ((kt + 2) % 3) * 24576;
    if (kt + 1 < NKT) asm volatile("s_waitcnt vmcnt(3)" ::: "memory");
    else              asm volatile("s_waitcnt vmcnt(0)" ::: "memory");
    __builtin_amdgcn_s_barrier();
    __builtin_amdgcn_sched_barrier(0);
    if (kt + 2 < NKT){ STG(0, kt+2, sOff); STG(1, kt+2, sOff); STG(2, kt+2, sOff); }
    s16x8 af[4], bfr[4];
    #pragma unroll
    for (int f = 0; f < 4; ++f)
      af[f] = *reinterpret_cast<const s16x8*>(lds + rOff + aoff[f]);
    #pragma unroll
    for (int f = 0; f < 4; ++f)
      bfr[f] = *reinterpret_cast<const s16x8*>(lds + rOff + boff[f]);
    __builtin_amdgcn_s_setprio(1);
    #pragma unroll
    for (int mi = 0; mi < 4; ++mi)
      #pragma unroll
      for (int ni = 0; ni < 4; ++ni)
        acc[mi][ni] = __builtin_amdgcn_mfma_f32_16x16x32_bf16(bfr[ni], af[mi], acc[mi][ni], 0, 0, 0);
    __builtin_amdgcn_s_setprio(0);
  }
  __builtin_amdgcn_s_barrier();   // LDS reuse fence before epilogue

  if (MODE == 0){
    // swapped frags: token = mi*16 + lr (0..63), col = ni*16 + lg*4 + j (0..63 = one head)
    char* reg = lds + wid*8192;   // 64 tokens x 128B
    #pragma unroll
    for (int mi = 0; mi < 4; ++mi){
      #pragma unroll
      for (int ni = 0; ni < 4; ++ni){
        int tok = mi*16 + lr;
        int sl = (ni*4 + lg) ^ (tok & 15);
        ushort4 w4;
        w4.x = (unsigned short)f2bf(acc[mi][ni][0]);
        w4.y = (unsigned short)f2bf(acc[mi][ni][1]);
        w4.z = (unsigned short)f2bf(acc[mi][ni][2]);
        w4.w = (unsigned short)f2bf(acc[mi][ni][3]);
        *reinterpret_cast<unsigned long long*>(reg + tok*128 + sl*8) =
            *reinterpret_cast<unsigned long long*>(&w4);
      }
    }
    asm volatile("s_waitcnt lgkmcnt(0)" ::: "memory");
    __builtin_amdgcn_sched_barrier(0);
    int gcol = bn + wn64;
    int ts = gcol >> 9, rem = gcol & 511, h = rem >> 6;
    __hip_bfloat16* dstT = (ts == 0) ? oQ : ((ts == 1) ? oK : oV);
    int tokbase = bm + wm;
    int bb = tokbase >> 13;
    dstT += ((size_t)(bb*8 + h)) << 19;   // * SEQ * 64
    #pragma unroll
    for (int p2 = 0; p2 < 8; ++p2){
      int tok = p2*8 + (lane >> 3);
      int l0 = (lane & 7) * 2;
      unsigned long long u0 = *reinterpret_cast<const unsigned long long*>(reg + tok*128 + ((l0 ^ (tok & 15)))*8);
      unsigned long long u1 = *reinterpret_cast<const unsigned long long*>(reg + tok*128 + (((l0+1) ^ (tok & 15)))*8);
      int n = (tokbase + tok) & 8191;
      unsigned long long o2[2] = { u0, u1 };
      *reinterpret_cast<s16x8*>(dstT + ((size_t)n << 6) + (lane & 7)*8) =
          *reinterpret_cast<const s16x8*>(o2);
    }
  } else {
    #pragma unroll
    for (int mi = 0; mi < 4; ++mi){
      #pragma unroll
      for (int ni = 0; ni < 4; ++ni){
        int gc = bn + wn64 + ni*16 + lg*4;
        int gr = bm + wm + mi*16 + lr;
        float4 bv = *reinterpret_cast<const float4*>(bias + gc);
        float4 o;
        o.x = acc[mi][ni][0] + bv.x;
        o.y = acc[mi][ni][1] + bv.y;
        o.z = acc[mi][ni][2] + bv.z;
        o.w = acc[mi][ni][3] + bv.w;
        *reinterpret_cast<float4*>(oF + (size_t)gr*Nn + gc) = o;
      }
    }
  }
  #undef STG
  #undef SWR
}

// ---------------- fused score+accum partials (vectorized accum: 8 tokens x 16B/lane) ----------------
// SRC 0: sv = svec * 0.125 (q-path).  SRC 1: sv = combine(partsIn)/tot * wkl[d/2] * 0.125 (k-path).
template<int SRC>
__global__ __launch_bounds__(256) void fused_stats(
    const __hip_bfloat16* __restrict__ T, const float* __restrict__ svec,
    const float* __restrict__ partsIn, const float* __restrict__ wkl,
    const unsigned* __restrict__ tab, float* __restrict__ outp)
{
  int chunk = blockIdx.x, bh = blockIdx.y;
  int t = threadIdx.x, lane = t & 63, w = t >> 6;
  __shared__ float sv[64];
  __shared__ float ev[256];
  __shared__ float redv[4][64];
  __shared__ float rede[4];
  if (t < 64){
    float s;
    if (SRC == 0){
      s = svec[t] * 0.125f;
    } else {
      const float* pp = partsIn;
      float tot = 0.f, g = 0.f;
      #pragma unroll 4
      for (int i = 0; i < 32; ++i){ tot += pp[i*66 + 1]; g += pp[i*66 + 2 + t]; }
      s = (g / tot) * wkl[t >> 1] * 0.125f;
    }
    sv[t] = s;
  }
  __syncthreads();

  // ---- score pass: thread t <-> token t ----
  int n = chunk*256 + t;
  const __hip_bfloat16* row = T + ((size_t)bh*SEQ + n)*64;
  float s = 0.f;
  #pragma unroll
  for (int dv = 0; dv < 8; ++dv){
    s16x8 v8 = *reinterpret_cast<const s16x8*>(row + dv*8);
    #pragma unroll
    for (int e = 0; e < 8; ++e) s += bf2f(v8[e]) * sv[dv*8 + e];
  }
  ev[t] = __expf(s);
  __syncthreads();

  // ---- accum pass: wave w handles tokens [w*64, w*64+64), 8 tokens/iter ----
  const short* Tb = reinterpret_cast<const short*>(T + ((size_t)bh*SEQ + chunk*256)*64);
  const unsigned* tabb = tab + (size_t)chunk*256*64;
  int g = lane >> 3, j = lane & 7;
  float acc[8] = {0.f,0.f,0.f,0.f,0.f,0.f,0.f,0.f};
  float se = 0.f;
  int tokw = w*64;
  #pragma unroll
  for (int i = 0; i < 8; ++i){
    int tok = tokw + i*8 + g;
    float e = ev[tok];
    s16x8 v8 = *reinterpret_cast<const s16x8*>(Tb + (size_t)tok*64 + j*8);
    uint4 t0 = *reinterpret_cast<const uint4*>(tabb + (size_t)tok*64 + j*8);
    uint4 t1 = *reinterpret_cast<const uint4*>(tabb + (size_t)tok*64 + j*8 + 4);
    #pragma unroll
    for (int e2 = 0; e2 < 8; ++e2){
      unsigned u = (e2 < 4) ? ((const unsigned*)&t0)[e2] : ((const unsigned*)&t1)[e2-4];
      float c  = bf2f((short)(u & 0xffff));
      float s2 = bf2f((short)(u >> 16));
      float xv = bf2f(v8[e2]);
      float xo = bf2f(v8[e2 ^ 1]);
      acc[e2] += e * (xv*c + xo*s2);
    }
    se += e;
  }
  // reduce over g (lane bits 3..5)
  #pragma unroll
  for (int m = 8; m <= 32; m <<= 1){
    #pragma unroll
    for (int e2 = 0; e2 < 8; ++e2) acc[e2] += __shfl_xor(acc[e2], m, 64);
    se += __shfl_xor(se, m, 64);
  }
  if (lane < 8){
    float4 a0 = { acc[0], acc[1], acc[2], acc[3] };
    float4 a1 = { acc[4], acc[5], acc[6], acc[7] };
    *reinterpret_cast<float4*>(&redv[w][lane*8])     = a0;
    *reinterpret_cast<float4*>(&redv[w][lane*8 + 4]) = a1;
  }
  if (lane == 0) rede[w] = se;
  __syncthreads();
  if (t < 64){
    float* ob = outp + (size_t)(bh*32 + chunk)*66;
    ob[2 + t] = redv[0][t] + redv[1][t] + redv[2][t] + redv[3][t];
    if (t == 0) ob[1] = rede[0] + rede[1] + rede[2] + rede[3];
  }
}

// ---------------- per-token epilogue: gk from partsK; u = pairsum(v*gk); r = u@w_r + b_r + q ----------------
__global__ __launch_bounds__(256) void epilogue_r(
    const __hip_bfloat16* __restrict__ vT, const __hip_bfloat16* __restrict__ qT,
    const float* __restrict__ partsK, const float* __restrict__ wr, const float* __restrict__ br,
    __hip_bfloat16* __restrict__ rb)
{
  int idx = blockIdx.x*256 + threadIdx.x;
  int bh = idx >> 13, nl = idx & 8191;
  int b = bh >> 3, h = bh & 7;
  int t = threadIdx.x;
  __shared__ float sgk[64];
  if (t < 64){
    const float* pp = partsK + (size_t)bh*32*66;
    float tot = 0.f, g = 0.f;
    #pragma unroll 4
    for (int i = 0; i < 32; ++i){ tot += pp[i*66 + 1]; g += pp[i*66 + 2 + t]; }
    sgk[t] = g / tot;
  }
  __syncthreads();

  const __hip_bfloat16* vrow = vT + (size_t)idx*64;
  const __hip_bfloat16* qrow = qT + (size_t)idx*64;
  float u[32];
  #pragma unroll
  for (int dv = 0; dv < 8; ++dv){
    s16x8 v8 = *reinterpret_cast<const s16x8*>(vrow + dv*8);
    #pragma unroll
    for (int e = 0; e < 8; e += 2){
      int d = dv*8 + e;
      u[d >> 1] = bf2f(v8[e])*sgk[d] + bf2f(v8[e+1])*sgk[d+1];
    }
  }
  __hip_bfloat16* rrow = rb + ((size_t)(b*SEQ + nl))*512 + h*64;
  #pragma unroll 2
  for (int dv = 0; dv < 8; ++dv){
    s16x8 q8 = *reinterpret_cast<const s16x8*>(qrow + dv*8);
    s16x8 o8;
    #pragma unroll
    for (int e = 0; e < 8; ++e){
      int d = dv*8 + e;
      float a2 = br[d] + bf2f(q8[e]);
      #pragma unroll
      for (int j = 0; j < 32; ++j) a2 += u[j] * wr[j*64 + d];
      o8[e] = f2bf(a2);
    }
    *reinterpret_cast<s16x8*>(rrow + dv*8) = o8;
  }
}

extern "C" void kernel_launch(void* const* d_in, const int* in_sizes, int n_in,
                              void* d_out, int out_size, void* d_ws, size_t ws_size,
                              hipStream_t stream)
{
  (void)in_sizes; (void)n_in; (void)out_size; (void)ws_size;
  const float* x    = (const float*)d_in[0];
  const float* wqkv = (const float*)d_in[1];
  const float* wql  = (const float*)d_in[2];
  const float* wkl  = (const float*)d_in[3];
  const float* wr   = (const float*)d_in[4];
  const float* br   = (const float*)d_in[5];
  const float* wout = (const float*)d_in[6];
  const float* bout = (const float*)d_in[7];
  float* out = (float*)d_out;

  char* p = (char*)d_ws;
  auto alloc = [&](size_t bytes){ char* r = p; p += (bytes + 255) & ~(size_t)255; return r; };
  __hip_bfloat16* xb    = (__hip_bfloat16*)alloc(33554432);
  __hip_bfloat16* wqkvT = (__hip_bfloat16*)alloc(1572864);
  __hip_bfloat16* woutT = (__hip_bfloat16*)alloc(524288);
  __hip_bfloat16* qT = (__hip_bfloat16*)alloc(33554432);
  __hip_bfloat16* kT = (__hip_bfloat16*)alloc(33554432);
  __hip_bfloat16* vT = (__hip_bfloat16*)alloc(33554432);
  __hip_bfloat16* rb = (__hip_bfloat16*)alloc(33554432);
  unsigned* tab = (unsigned*)alloc(2097152);   // packed bf16 cos/sin [8192][64]

  float* partsQ = (float*)xb;          // aliases xb (dead after gemm1)
  float* partsK = partsQ + 32*32*66;

  prep<<<19456, 256, 0, stream>>>(x, xb, tab, wqkv, wqkvT, wout, woutT);

  gemm128<0><<<1536, 512, 0, stream>>>(xb, wqkvT, 32768, 1536,
                                       qT, kT, vT, nullptr, nullptr);

  fused_stats<0><<<dim3(32,32), 256, 0, stream>>>(qT, wql, nullptr, nullptr, tab, partsQ);
  fused_stats<1><<<dim3(32,32), 256, 0, stream>>>(kT, nullptr, partsQ, wkl, tab, partsK);

  epilogue_r<<<1024, 256, 0, stream>>>(vT, qT, partsK, wr, br, rb);

  gemm128<1><<<512, 512, 0, stream>>>(rb, woutT, 32768, 512,
                                      nullptr, nullptr, nullptr, out, bout);
}

// Round 14
// 180.845 us; speedup vs baseline: 1.0329x; 1.0329x over previous
//
#include <hip/hip_runtime.h>
#include <hip/hip_bf16.h>

typedef __attribute__((ext_vector_type(8))) short s16x8;
typedef __attribute__((ext_vector_type(4))) short s16x4;
typedef __attribute__((ext_vector_type(4))) float f32x4;

#define SEQ 8192

__device__ __forceinline__ float bf2f(short s){
  union { unsigned u; float f; } c; c.u = ((unsigned)(unsigned short)s) << 16; return c.f;
}
__device__ __forceinline__ short f2bf(float f){
  __hip_bfloat16 h = __float2bfloat16(f);
  short s; __builtin_memcpy(&s, &h, 2); return s;
}

// ---------------- transpose tile body (fp32 (R,C) -> bf16 (C,R)) ----------------
__device__ __forceinline__ void transpose_body(const float* __restrict__ in, __hip_bfloat16* __restrict__ out,
                                               int R, int C, int bx, int by){
  __shared__ float tile[32][33];
  int c0 = bx*32, r0 = by*32;
  int tx = threadIdx.x & 31, ty = threadIdx.x >> 5;
  #pragma unroll
  for (int i = ty; i < 32; i += 8) tile[i][tx] = in[(size_t)(r0+i)*C + c0 + tx];
  __syncthreads();
  #pragma unroll
  for (int i = ty; i < 32; i += 8) out[(size_t)(c0+i)*R + r0 + tx] = __float2bfloat16(tile[tx][i]);
}

// ---------------- fused prep: cvt_x | rotary table | transposes ----------------
__global__ __launch_bounds__(256) void prep(
    const float* __restrict__ x, __hip_bfloat16* __restrict__ xb, unsigned* __restrict__ tab,
    const float* __restrict__ wqkv, __hip_bfloat16* __restrict__ wqkvT,
    const float* __restrict__ wout, __hip_bfloat16* __restrict__ woutT)
{
  int b = blockIdx.x;
  if (b < 16384){
    int i = b*256 + threadIdx.x;
    float4 v = reinterpret_cast<const float4*>(x)[i];
    s16x4 o = { f2bf(v.x), f2bf(v.y), f2bf(v.z), f2bf(v.w) };
    reinterpret_cast<s16x4*>(xb)[i] = o;
  } else if (b < 18432){
    int idx = (b - 16384)*256 + threadIdx.x;   // n*64 + d
    int n = idx >> 6, d = idx & 63;
    float c, s;
    if (d < 32){
      float ex = -(float)(d & ~1) / 32.0f;
      float invf = __expf(ex * 9.210340371976184f);   // 10000^ex
      float f = (float)n * invf;
      __sincosf(f, &s, &c);
      s = (d & 1) ? s : -s;
    } else { c = 1.f; s = 0.f; }
    tab[idx] = (unsigned)(unsigned short)f2bf(c) | ((unsigned)(unsigned short)f2bf(s) << 16);
  } else if (b < 19200){
    int id = b - 18432;                        // 48 x 16 tiles
    transpose_body(wqkv, wqkvT, 512, 1536, id % 48, id / 48);
  } else {
    int id = b - 19200;                        // 16 x 16 tiles
    transpose_body(wout, woutT, 512, 512, id % 16, id / 16);
  }
}

// ================= 128x256 GEMM, BK=32, 3 LDS buffers (72KB), 2 blocks/CU (R11 schedule, frozen) =================
// NOTE: 2 blocks/CU is the occupancy ceiling for this geometry — 3 blocks/CU needs <=85 VGPR
// (launch_bounds(512,6)) which spills the 64-VGPR accumulator (R10: 1.37GB scratch writes, 5% MfmaUtil).
// MODE 0: q/k/v scatter via 8KB/wave LDS roundtrip (coalesced 16B bf16 stores).
// MODE 1: fp32 out + bias via 4KB/wave LDS roundtrip (256B row-contiguous fp32 stores).
template<int MODE>
__global__ __launch_bounds__(512, 4) void gemm128(
    const __hip_bfloat16* __restrict__ A, const __hip_bfloat16* __restrict__ BT,
    int M, int Nn, int K,
    __hip_bfloat16* __restrict__ oQ, __hip_bfloat16* __restrict__ oK, __hip_bfloat16* __restrict__ oV,
    float* __restrict__ oF, const float* __restrict__ bias)
{
  __shared__ __align__(16) char lds[73728];   // 3 x (A 128x32 + B 256x32) bf16 = 3 x 24KB
  const int t = threadIdx.x;
  const int lane = t & 63, wid = t >> 6;
  const int lr = lane & 15, lg = lane >> 4;
  const int wm   = (wid >> 2) * 64;    // 0,64
  const int wn64 = (wid & 3) * 64;     // 0..192

  // XCD-bijective swizzle, bn-fastest: each XCD owns a contiguous M-band (A-band ~4MB = its L2)
  int nwg = gridDim.x, per = nwg >> 3, wg = blockIdx.x;
  int swz = (wg & 7) * per + (wg >> 3);
  int nblk = Nn >> 8;                  // 256-col tiles
  int bm = (swz / nblk) << 7;          // 128-row tiles
  int bn = (swz % nblk) << 8;

  const int NKT = K >> 5;              // BK=32

  // staging: 1536 granules of 16B per tile; 3/thread. Source chunk pre-swizzled with
  // s(row) = (row>>1)&3 (involution with read XOR; bank = 16*(r&1)+4*chunk -> 2-way max)
  const __hip_bfloat16* spp[3];
  int dofs[3];
  #pragma unroll
  for (int i = 0; i < 3; ++i){
    int g = (i == 0) ? t : (t + (i-1)*512);
    int row = g >> 2, ch = g & 3;
    int sch = ch ^ ((row >> 1) & 3);
    spp[i] = (i == 0 ? A + (size_t)(bm + row)*K : BT + (size_t)(bn + row)*K) + sch*8;
    dofs[i] = ((i == 0) ? 0 : 8192) + g*16;
  }
  #define STG(i, kt2, bufo) __builtin_amdgcn_global_load_lds( \
      (const __attribute__((address_space(1))) void*)(spp[i] + (size_t)(kt2)*32), \
      (__attribute__((address_space(3))) void*)(lds + (bufo) + dofs[i]), 16, 0, 0)

  // prologue: stage tiles 0,1 into bufs 0,1
  STG(0, 0, 0); STG(1, 0, 0); STG(2, 0, 0);
  STG(0, 1, 24576); STG(1, 1, 24576); STG(2, 1, 24576);

  f32x4 acc[4][4] = {};
  int rOff = 0, sOff = 49152;          // read buf, stage buf byte offsets
  #define SWR(r) ((((r) >> 1) & 3) << 4)

  for (int kt = 0; kt < NKT; ++kt){
    if (kt + 1 < NKT) asm volatile("s_waitcnt vmcnt(3)" ::: "memory");
    else              asm volatile("s_waitcnt vmcnt(0)" ::: "memory");
    __builtin_amdgcn_s_barrier();
    __builtin_amdgcn_sched_barrier(0);
    if (kt + 2 < NKT){ STG(0, kt+2, sOff); STG(1, kt+2, sOff); STG(2, kt+2, sOff); }
    const char* lb = lds + rOff;
    s16x8 af[4], bfr[4];
    #pragma unroll
    for (int f = 0; f < 4; ++f){
      int r = wm + f*16 + lr;
      af[f] = *reinterpret_cast<const s16x8*>(lb + (r << 6) + ((lg << 4) ^ SWR(r)));
    }
    #pragma unroll
    for (int f = 0; f < 4; ++f){
      int r = wn64 + f*16 + lr;
      bfr[f] = *reinterpret_cast<const s16x8*>(lb + 8192 + (r << 6) + ((lg << 4) ^ SWR(r)));
    }
    __builtin_amdgcn_s_setprio(1);
    #pragma unroll
    for (int mi = 0; mi < 4; ++mi)
      #pragma unroll
      for (int ni = 0; ni < 4; ++ni)
        acc[mi][ni] = __builtin_amdgcn_mfma_f32_16x16x32_bf16(bfr[ni], af[mi], acc[mi][ni], 0, 0, 0);
    __builtin_amdgcn_s_setprio(0);
    rOff = (rOff == 49152) ? 0 : rOff + 24576;
    sOff = (sOff == 49152) ? 0 : sOff + 24576;
  }
  __builtin_amdgcn_s_barrier();   // LDS reuse fence before epilogue

  if (MODE == 0){
    // swapped frags: token = mi*16 + lr (0..63), col = ni*16 + lg*4 + j (0..63 = one head)
    char* reg = lds + wid*8192;   // 64 tokens x 128B
    #pragma unroll
    for (int mi = 0; mi < 4; ++mi){
      #pragma unroll
      for (int ni = 0; ni < 4; ++ni){
        int tok = mi*16 + lr;
        int sl = (ni*4 + lg) ^ (tok & 15);
        ushort4 w4;
        w4.x = (unsigned short)f2bf(acc[mi][ni][0]);
        w4.y = (unsigned short)f2bf(acc[mi][ni][1]);
        w4.z = (unsigned short)f2bf(acc[mi][ni][2]);
        w4.w = (unsigned short)f2bf(acc[mi][ni][3]);
        *reinterpret_cast<unsigned long long*>(reg + tok*128 + sl*8) =
            *reinterpret_cast<unsigned long long*>(&w4);
      }
    }
    asm volatile("s_waitcnt lgkmcnt(0)" ::: "memory");
    __builtin_amdgcn_sched_barrier(0);
    int gcol = bn + wn64;
    int ts = gcol >> 9, rem = gcol & 511, h = rem >> 6;
    __hip_bfloat16* dstT = (ts == 0) ? oQ : ((ts == 1) ? oK : oV);
    int tokbase = bm + wm;
    int bb = tokbase >> 13;
    dstT += ((size_t)(bb*8 + h)) << 19;   // * SEQ * 64
    #pragma unroll
    for (int p2 = 0; p2 < 8; ++p2){
      int tok = p2*8 + (lane >> 3);
      int l0 = (lane & 7) * 2;
      unsigned long long u0 = *reinterpret_cast<const unsigned long long*>(reg + tok*128 + ((l0 ^ (tok & 15)))*8);
      unsigned long long u1 = *reinterpret_cast<const unsigned long long*>(reg + tok*128 + (((l0+1) ^ (tok & 15)))*8);
      int n = (tokbase + tok) & 8191;
      unsigned long long o2[2] = { u0, u1 };
      *reinterpret_cast<s16x8*>(dstT + ((size_t)n << 6) + (lane & 7)*8) =
          *reinterpret_cast<const s16x8*>(o2);
    }
  } else {
    // fp32 + bias via per-wave 4KB LDS roundtrip -> 256B row-contiguous stores (full cache lines)
    char* reg = lds + wid*4096;          // 16 rows x 256B
    int sr = lane & 15;                  // 16B slot within row
    int rbase = lane >> 4;               // 0..3
    float4 bv = *reinterpret_cast<const float4*>(bias + bn + wn64 + sr*4);
    #pragma unroll
    for (int mi = 0; mi < 4; ++mi){
      #pragma unroll
      for (int ni = 0; ni < 4; ++ni){
        int sl = (ni*4 + lg) ^ lr;       // slot XOR swizzle (2-way bank max)
        *reinterpret_cast<f32x4*>(reg + lr*256 + sl*16) = acc[mi][ni];
      }
      asm volatile("s_waitcnt lgkmcnt(0)" ::: "memory");
      __builtin_amdgcn_sched_barrier(0);
      #pragma unroll
      for (int p = 0; p < 4; ++p){
        int row16 = p*4 + rbase;
        int sl = sr ^ row16;
        float4 v = *reinterpret_cast<const float4*>(reg + row16*256 + sl*16);
        int gr = bm + wm + mi*16 + row16;
        float4 o = { v.x + bv.x, v.y + bv.y, v.z + bv.z, v.w + bv.w };
        *reinterpret_cast<float4*>(oF + (size_t)gr*Nn + bn + wn64 + sr*4) = o;
      }
      asm volatile("s_waitcnt lgkmcnt(0)" ::: "memory");   // reads done before next mi overwrites
      __builtin_amdgcn_sched_barrier(0);
    }
  }
  #undef STG
  #undef SWR
}

// ---------------- fused score+accum partials (vectorized accum: 8 tokens x 16B/lane) ----------------
// SRC 0: sv = svec * 0.125 (q-path).  SRC 1: sv = combine(partsIn)/tot * wkl[d/2] * 0.125 (k-path).
template<int SRC>
__global__ __launch_bounds__(256) void fused_stats(
    const __hip_bfloat16* __restrict__ T, const float* __restrict__ svec,
    const float* __restrict__ partsIn, const float* __restrict__ wkl,
    const unsigned* __restrict__ tab, float* __restrict__ outp)
{
  int chunk = blockIdx.x, bh = blockIdx.y;
  int t = threadIdx.x, lane = t & 63, w = t >> 6;
  __shared__ float sv[64];
  __shared__ float ev[256];
  __shared__ float redv[4][64];
  __shared__ float rede[4];
  if (t < 64){
    float s;
    if (SRC == 0){
      s = svec[t] * 0.125f;
    } else {
      const float* pp = partsIn;
      float tot = 0.f, g = 0.f;
      #pragma unroll 4
      for (int i = 0; i < 32; ++i){ tot += pp[i*66 + 1]; g += pp[i*66 + 2 + t]; }
      s = (g / tot) * wkl[t >> 1] * 0.125f;
    }
    sv[t] = s;
  }
  __syncthreads();

  // ---- score pass: thread t <-> token t ----
  int n = chunk*256 + t;
  const __hip_bfloat16* row = T + ((size_t)bh*SEQ + n)*64;
  float s = 0.f;
  #pragma unroll
  for (int dv = 0; dv < 8; ++dv){
    s16x8 v8 = *reinterpret_cast<const s16x8*>(row + dv*8);
    #pragma unroll
    for (int e = 0; e < 8; ++e) s += bf2f(v8[e]) * sv[dv*8 + e];
  }
  ev[t] = __expf(s);
  __syncthreads();

  // ---- accum pass: wave w handles tokens [w*64, w*64+64), 8 tokens/iter ----
  const short* Tb = reinterpret_cast<const short*>(T + ((size_t)bh*SEQ + chunk*256)*64);
  const unsigned* tabb = tab + (size_t)chunk*256*64;
  int g = lane >> 3, j = lane & 7;
  float acc[8] = {0.f,0.f,0.f,0.f,0.f,0.f,0.f,0.f};
  float se = 0.f;
  int tokw = w*64;
  #pragma unroll
  for (int i = 0; i < 8; ++i){
    int tok = tokw + i*8 + g;
    float e = ev[tok];
    s16x8 v8 = *reinterpret_cast<const s16x8*>(Tb + (size_t)tok*64 + j*8);
    uint4 t0 = *reinterpret_cast<const uint4*>(tabb + (size_t)tok*64 + j*8);
    uint4 t1 = *reinterpret_cast<const uint4*>(tabb + (size_t)tok*64 + j*8 + 4);
    #pragma unroll
    for (int e2 = 0; e2 < 8; ++e2){
      unsigned u = (e2 < 4) ? ((const unsigned*)&t0)[e2] : ((const unsigned*)&t1)[e2-4];
      float c  = bf2f((short)(u & 0xffff));
      float s2 = bf2f((short)(u >> 16));
      float xv = bf2f(v8[e2]);
      float xo = bf2f(v8[e2 ^ 1]);
      acc[e2] += e * (xv*c + xo*s2);
    }
    se += e;
  }
  // reduce over g (lane bits 3..5)
  #pragma unroll
  for (int m = 8; m <= 32; m <<= 1){
    #pragma unroll
    for (int e2 = 0; e2 < 8; ++e2) acc[e2] += __shfl_xor(acc[e2], m, 64);
    se += __shfl_xor(se, m, 64);
  }
  if (lane < 8){
    float4 a0 = { acc[0], acc[1], acc[2], acc[3] };
    float4 a1 = { acc[4], acc[5], acc[6], acc[7] };
    *reinterpret_cast<float4*>(&redv[w][lane*8])     = a0;
    *reinterpret_cast<float4*>(&redv[w][lane*8 + 4]) = a1;
  }
  if (lane == 0) rede[w] = se;
  __syncthreads();
  if (t < 64){
    float* ob = outp + (size_t)(bh*32 + chunk)*66;
    ob[2 + t] = redv[0][t] + redv[1][t] + redv[2][t] + redv[3][t];
    if (t == 0) ob[1] = rede[0] + rede[1] + rede[2] + rede[3];
  }
}

// ---------------- per-token epilogue: gk from partsK; u = pairsum(v*gk); r = u@w_r + b_r + q ----------------
__global__ __launch_bounds__(256) void epilogue_r(
    const __hip_bfloat16* __restrict__ vT, const __hip_bfloat16* __restrict__ qT,
    const float* __restrict__ partsK, const float* __restrict__ wr, const float* __restrict__ br,
    __hip_bfloat16* __restrict__ rb)
{
  int idx = blockIdx.x*256 + threadIdx.x;
  int bh = idx >> 13, nl = idx & 8191;
  int b = bh >> 3, h = bh & 7;
  int t = threadIdx.x;
  __shared__ float sgk[64];
  if (t < 64){
    const float* pp = partsK + (size_t)bh*32*66;
    float tot = 0.f, g = 0.f;
    #pragma unroll 4
    for (int i = 0; i < 32; ++i){ tot += pp[i*66 + 1]; g += pp[i*66 + 2 + t]; }
    sgk[t] = g / tot;
  }
  __syncthreads();

  const __hip_bfloat16* vrow = vT + (size_t)idx*64;
  const __hip_bfloat16* qrow = qT + (size_t)idx*64;
  float u[32];
  #pragma unroll
  for (int dv = 0; dv < 8; ++dv){
    s16x8 v8 = *reinterpret_cast<const s16x8*>(vrow + dv*8);
    #pragma unroll
    for (int e = 0; e < 8; e += 2){
      int d = dv*8 + e;
      u[d >> 1] = bf2f(v8[e])*sgk[d] + bf2f(v8[e+1])*sgk[d+1];
    }
  }
  __hip_bfloat16* rrow = rb + ((size_t)(b*SEQ + nl))*512 + h*64;
  #pragma unroll 2
  for (int dv = 0; dv < 8; ++dv){
    s16x8 q8 = *reinterpret_cast<const s16x8*>(qrow + dv*8);
    s16x8 o8;
    #pragma unroll
    for (int e = 0; e < 8; ++e){
      int d = dv*8 + e;
      float a2 = br[d] + bf2f(q8[e]);
      #pragma unroll
      for (int j = 0; j < 32; ++j) a2 += u[j] * wr[j*64 + d];
      o8[e] = f2bf(a2);
    }
    *reinterpret_cast<s16x8*>(rrow + dv*8) = o8;
  }
}

extern "C" void kernel_launch(void* const* d_in, const int* in_sizes, int n_in,
                              void* d_out, int out_size, void* d_ws, size_t ws_size,
                              hipStream_t stream)
{
  (void)in_sizes; (void)n_in; (void)out_size; (void)ws_size;
  const float* x    = (const float*)d_in[0];
  const float* wqkv = (const float*)d_in[1];
  const float* wql  = (const float*)d_in[2];
  const float* wkl  = (const float*)d_in[3];
  const float* wr   = (const float*)d_in[4];
  const float* br   = (const float*)d_in[5];
  const float* wout = (const float*)d_in[6];
  const float* bout = (const float*)d_in[7];
  float* out = (float*)d_out;

  char* p = (char*)d_ws;
  auto alloc = [&](size_t bytes){ char* r = p; p += (bytes + 255) & ~(size_t)255; return r; };
  __hip_bfloat16* xb    = (__hip_bfloat16*)alloc(33554432);
  __hip_bfloat16* wqkvT = (__hip_bfloat16*)alloc(1572864);
  __hip_bfloat16* woutT = (__hip_bfloat16*)alloc(524288);
  __hip_bfloat16* qT = (__hip_bfloat16*)alloc(33554432);
  __hip_bfloat16* kT = (__hip_bfloat16*)alloc(33554432);
  __hip_bfloat16* vT = (__hip_bfloat16*)alloc(33554432);
  __hip_bfloat16* rb = (__hip_bfloat16*)alloc(33554432);
  unsigned* tab = (unsigned*)alloc(2097152);   // packed bf16 cos/sin [8192][64]

  float* partsQ = (float*)xb;          // aliases xb (dead after gemm1)
  float* partsK = partsQ + 32*32*66;

  prep<<<19456, 256, 0, stream>>>(x, xb, tab, wqkv, wqkvT, wout, woutT);

  gemm128<0><<<1536, 512, 0, stream>>>(xb, wqkvT, 32768, 1536, 512,
                                       qT, kT, vT, nullptr, nullptr);

  fused_stats<0><<<dim3(32,32), 256, 0, stream>>>(qT, wql, nullptr, nullptr, tab, partsQ);
  fused_stats<1><<<dim3(32,32), 256, 0, stream>>>(kT, nullptr, partsQ, wkl, tab, partsK);

  epilogue_r<<<1024, 256, 0, stream>>>(vT, qT, partsK, wr, br, rb);

  gemm128<1><<<512, 512, 0, stream>>>(rb, woutT, 32768, 512, 512,
                                      nullptr, nullptr, nullptr, out, bout);
}

// Round 16
// 180.358 us; speedup vs baseline: 1.0357x; 1.0027x over previous
//
#include <hip/hip_runtime.h>
#include <hip/hip_bf16.h>

typedef __attribute__((ext_vector_type(8))) short s16x8;
typedef __attribute__((ext_vector_type(4))) short s16x4;
typedef __attribute__((ext_vector_type(4))) float f32x4;

#define SEQ 8192

__device__ __forceinline__ float bf2f(short s){
  union { unsigned u; float f; } c; c.u = ((unsigned)(unsigned short)s) << 16; return c.f;
}
__device__ __forceinline__ short f2bf(float f){
  __hip_bfloat16 h = __float2bfloat16(f);
  short s; __builtin_memcpy(&s, &h, 2); return s;
}

// ---------------- transpose tile body (fp32 (R,C) -> bf16 (C,R)) ----------------
__device__ __forceinline__ void transpose_body(const float* __restrict__ in, __hip_bfloat16* __restrict__ out,
                                               int R, int C, int bx, int by){
  __shared__ float tile[32][33];
  int c0 = bx*32, r0 = by*32;
  int tx = threadIdx.x & 31, ty = threadIdx.x >> 5;
  #pragma unroll
  for (int i = ty; i < 32; i += 8) tile[i][tx] = in[(size_t)(r0+i)*C + c0 + tx];
  __syncthreads();
  #pragma unroll
  for (int i = ty; i < 32; i += 8) out[(size_t)(c0+i)*R + r0 + tx] = __float2bfloat16(tile[tx][i]);
}

// ---------------- fused prep: cvt_x | rotary table | transposes ----------------
__global__ __launch_bounds__(256) void prep(
    const float* __restrict__ x, __hip_bfloat16* __restrict__ xb, unsigned* __restrict__ tab,
    const float* __restrict__ wqkv, __hip_bfloat16* __restrict__ wqkvT,
    const float* __restrict__ wout, __hip_bfloat16* __restrict__ woutT)
{
  int b = blockIdx.x;
  if (b < 16384){
    int i = b*256 + threadIdx.x;
    float4 v = reinterpret_cast<const float4*>(x)[i];
    s16x4 o = { f2bf(v.x), f2bf(v.y), f2bf(v.z), f2bf(v.w) };
    reinterpret_cast<s16x4*>(xb)[i] = o;
  } else if (b < 18432){
    int idx = (b - 16384)*256 + threadIdx.x;   // n*64 + d
    int n = idx >> 6, d = idx & 63;
    float c, s;
    if (d < 32){
      float ex = -(float)(d & ~1) / 32.0f;
      float invf = __expf(ex * 9.210340371976184f);   // 10000^ex
      float f = (float)n * invf;
      __sincosf(f, &s, &c);
      s = (d & 1) ? s : -s;
    } else { c = 1.f; s = 0.f; }
    tab[idx] = (unsigned)(unsigned short)f2bf(c) | ((unsigned)(unsigned short)f2bf(s) << 16);
  } else if (b < 19200){
    int id = b - 18432;                        // 48 x 16 tiles
    transpose_body(wqkv, wqkvT, 512, 1536, id % 48, id / 48);
  } else {
    int id = b - 19200;                        // 16 x 16 tiles
    transpose_body(wout, woutT, 512, 512, id % 16, id / 16);
  }
}

// ================= 128x256 GEMM, BK=32, 3 LDS buffers (72KB), 2 blocks/CU (R11 schedule, frozen) =================
// NOTE: 2 blocks/CU is the occupancy ceiling for this geometry — 3 blocks/CU needs <=85 VGPR
// (launch_bounds(512,6)) which spills the 64-VGPR accumulator (R10: 1.37GB scratch writes, 5% MfmaUtil).
// MODE 0: q/k/v scatter via 8KB/wave LDS roundtrip (coalesced 16B bf16 stores).
// MODE 1: fp32 out + bias via 4KB/wave LDS roundtrip (256B row-contiguous fp32 stores).
template<int MODE>
__global__ __launch_bounds__(512, 4) void gemm128(
    const __hip_bfloat16* __restrict__ A, const __hip_bfloat16* __restrict__ BT,
    int M, int Nn, int K,
    __hip_bfloat16* __restrict__ oQ, __hip_bfloat16* __restrict__ oK, __hip_bfloat16* __restrict__ oV,
    float* __restrict__ oF, const float* __restrict__ bias)
{
  __shared__ __align__(16) char lds[73728];   // 3 x (A 128x32 + B 256x32) bf16 = 3 x 24KB
  const int t = threadIdx.x;
  const int lane = t & 63, wid = t >> 6;
  const int lr = lane & 15, lg = lane >> 4;
  const int wm   = (wid >> 2) * 64;    // 0,64
  const int wn64 = (wid & 3) * 64;     // 0..192

  // XCD-bijective swizzle, bn-fastest: each XCD owns a contiguous M-band (A-band ~4MB = its L2)
  int nwg = gridDim.x, per = nwg >> 3, wg = blockIdx.x;
  int swz = (wg & 7) * per + (wg >> 3);
  int nblk = Nn >> 8;                  // 256-col tiles
  int bm = (swz / nblk) << 7;          // 128-row tiles
  int bn = (swz % nblk) << 8;

  const int NKT = K >> 5;              // BK=32

  // staging: 1536 granules of 16B per tile; 3/thread. Source chunk pre-swizzled with
  // s(row) = (row>>1)&3 (involution with read XOR; bank = 16*(r&1)+4*chunk -> 2-way max)
  const __hip_bfloat16* spp[3];
  int dofs[3];
  #pragma unroll
  for (int i = 0; i < 3; ++i){
    int g = (i == 0) ? t : (t + (i-1)*512);
    int row = g >> 2, ch = g & 3;
    int sch = ch ^ ((row >> 1) & 3);
    spp[i] = (i == 0 ? A + (size_t)(bm + row)*K : BT + (size_t)(bn + row)*K) + sch*8;
    dofs[i] = ((i == 0) ? 0 : 8192) + g*16;
  }
  #define STG(i, kt2, bufo) __builtin_amdgcn_global_load_lds( \
      (const __attribute__((address_space(1))) void*)(spp[i] + (size_t)(kt2)*32), \
      (__attribute__((address_space(3))) void*)(lds + (bufo) + dofs[i]), 16, 0, 0)

  // prologue: stage tiles 0,1 into bufs 0,1
  STG(0, 0, 0); STG(1, 0, 0); STG(2, 0, 0);
  STG(0, 1, 24576); STG(1, 1, 24576); STG(2, 1, 24576);

  f32x4 acc[4][4] = {};
  int rOff = 0, sOff = 49152;          // read buf, stage buf byte offsets
  #define SWR(r) ((((r) >> 1) & 3) << 4)

  for (int kt = 0; kt < NKT; ++kt){
    if (kt + 1 < NKT) asm volatile("s_waitcnt vmcnt(3)" ::: "memory");
    else              asm volatile("s_waitcnt vmcnt(0)" ::: "memory");
    __builtin_amdgcn_s_barrier();
    __builtin_amdgcn_sched_barrier(0);
    if (kt + 2 < NKT){ STG(0, kt+2, sOff); STG(1, kt+2, sOff); STG(2, kt+2, sOff); }
    const char* lb = lds + rOff;
    s16x8 af[4], bfr[4];
    #pragma unroll
    for (int f = 0; f < 4; ++f){
      int r = wm + f*16 + lr;
      af[f] = *reinterpret_cast<const s16x8*>(lb + (r << 6) + ((lg << 4) ^ SWR(r)));
    }
    #pragma unroll
    for (int f = 0; f < 4; ++f){
      int r = wn64 + f*16 + lr;
      bfr[f] = *reinterpret_cast<const s16x8*>(lb + 8192 + (r << 6) + ((lg << 4) ^ SWR(r)));
    }
    __builtin_amdgcn_s_setprio(1);
    #pragma unroll
    for (int mi = 0; mi < 4; ++mi)
      #pragma unroll
      for (int ni = 0; ni < 4; ++ni)
        acc[mi][ni] = __builtin_amdgcn_mfma_f32_16x16x32_bf16(bfr[ni], af[mi], acc[mi][ni], 0, 0, 0);
    __builtin_amdgcn_s_setprio(0);
    rOff = (rOff == 49152) ? 0 : rOff + 24576;
    sOff = (sOff == 49152) ? 0 : sOff + 24576;
  }
  __builtin_amdgcn_s_barrier();   // LDS reuse fence before epilogue

  if (MODE == 0){
    // swapped frags: token = mi*16 + lr (0..63), col = ni*16 + lg*4 + j (0..63 = one head)
    char* reg = lds + wid*8192;   // 64 tokens x 128B
    #pragma unroll
    for (int mi = 0; mi < 4; ++mi){
      #pragma unroll
      for (int ni = 0; ni < 4; ++ni){
        int tok = mi*16 + lr;
        int sl = (ni*4 + lg) ^ (tok & 15);
        ushort4 w4;
        w4.x = (unsigned short)f2bf(acc[mi][ni][0]);
        w4.y = (unsigned short)f2bf(acc[mi][ni][1]);
        w4.z = (unsigned short)f2bf(acc[mi][ni][2]);
        w4.w = (unsigned short)f2bf(acc[mi][ni][3]);
        *reinterpret_cast<unsigned long long*>(reg + tok*128 + sl*8) =
            *reinterpret_cast<unsigned long long*>(&w4);
      }
    }
    asm volatile("s_waitcnt lgkmcnt(0)" ::: "memory");
    __builtin_amdgcn_sched_barrier(0);
    int gcol = bn + wn64;
    int ts = gcol >> 9, rem = gcol & 511, h = rem >> 6;
    __hip_bfloat16* dstT = (ts == 0) ? oQ : ((ts == 1) ? oK : oV);
    int tokbase = bm + wm;
    int bb = tokbase >> 13;
    dstT += ((size_t)(bb*8 + h)) << 19;   // * SEQ * 64
    #pragma unroll
    for (int p2 = 0; p2 < 8; ++p2){
      int tok = p2*8 + (lane >> 3);
      int l0 = (lane & 7) * 2;
      unsigned long long u0 = *reinterpret_cast<const unsigned long long*>(reg + tok*128 + ((l0 ^ (tok & 15)))*8);
      unsigned long long u1 = *reinterpret_cast<const unsigned long long*>(reg + tok*128 + (((l0+1) ^ (tok & 15)))*8);
      int n = (tokbase + tok) & 8191;
      unsigned long long o2[2] = { u0, u1 };
      *reinterpret_cast<s16x8*>(dstT + ((size_t)n << 6) + (lane & 7)*8) =
          *reinterpret_cast<const s16x8*>(o2);
    }
  } else {
    // fp32 + bias via per-wave 4KB LDS roundtrip -> 256B row-contiguous stores (full cache lines)
    char* reg = lds + wid*4096;          // 16 rows x 256B
    int sr = lane & 15;                  // 16B slot within row
    int rbase = lane >> 4;               // 0..3
    float4 bv = *reinterpret_cast<const float4*>(bias + bn + wn64 + sr*4);
    #pragma unroll
    for (int mi = 0; mi < 4; ++mi){
      #pragma unroll
      for (int ni = 0; ni < 4; ++ni){
        int sl = (ni*4 + lg) ^ lr;       // slot XOR swizzle (2-way bank max)
        *reinterpret_cast<f32x4*>(reg + lr*256 + sl*16) = acc[mi][ni];
      }
      asm volatile("s_waitcnt lgkmcnt(0)" ::: "memory");
      __builtin_amdgcn_sched_barrier(0);
      #pragma unroll
      for (int p = 0; p < 4; ++p){
        int row16 = p*4 + rbase;
        int sl = sr ^ row16;
        float4 v = *reinterpret_cast<const float4*>(reg + row16*256 + sl*16);
        int gr = bm + wm + mi*16 + row16;
        float4 o = { v.x + bv.x, v.y + bv.y, v.z + bv.z, v.w + bv.w };
        *reinterpret_cast<float4*>(oF + (size_t)gr*Nn + bn + wn64 + sr*4) = o;
      }
      asm volatile("s_waitcnt lgkmcnt(0)" ::: "memory");   // reads done before next mi overwrites
      __builtin_amdgcn_sched_barrier(0);
    }
  }
  #undef STG
  #undef SWR
}

// ---------------- fused score+accum partials (vectorized accum: 8 tokens x 16B/lane) ----------------
// SRC 0: sv = svec * 0.125 (q-path).  SRC 1: sv = combine(partsIn[bh])/tot * wkl[d/2] * 0.125 (k-path).
template<int SRC>
__global__ __launch_bounds__(256) void fused_stats(
    const __hip_bfloat16* __restrict__ T, const float* __restrict__ svec,
    const float* __restrict__ partsIn, const float* __restrict__ wkl,
    const unsigned* __restrict__ tab, float* __restrict__ outp)
{
  int chunk = blockIdx.x, bh = blockIdx.y;
  int t = threadIdx.x, lane = t & 63, w = t >> 6;
  __shared__ float sv[64];
  __shared__ float ev[256];
  __shared__ float redv[4][64];
  __shared__ float rede[4];
  if (t < 64){
    float s;
    if (SRC == 0){
      s = svec[t] * 0.125f;
    } else {
      const float* pp = partsIn + (size_t)bh*32*66;   // BUGFIX (R14): per-bh q-pool partials
      float tot = 0.f, g = 0.f;
      #pragma unroll 4
      for (int i = 0; i < 32; ++i){ tot += pp[i*66 + 1]; g += pp[i*66 + 2 + t]; }
      s = (g / tot) * wkl[t >> 1] * 0.125f;
    }
    sv[t] = s;
  }
  __syncthreads();

  // ---- score pass: thread t <-> token t ----
  int n = chunk*256 + t;
  const __hip_bfloat16* row = T + ((size_t)bh*SEQ + n)*64;
  float s = 0.f;
  #pragma unroll
  for (int dv = 0; dv < 8; ++dv){
    s16x8 v8 = *reinterpret_cast<const s16x8*>(row + dv*8);
    #pragma unroll
    for (int e = 0; e < 8; ++e) s += bf2f(v8[e]) * sv[dv*8 + e];
  }
  ev[t] = __expf(s);
  __syncthreads();

  // ---- accum pass: wave w handles tokens [w*64, w*64+64), 8 tokens/iter ----
  const short* Tb = reinterpret_cast<const short*>(T + ((size_t)bh*SEQ + chunk*256)*64);
  const unsigned* tabb = tab + (size_t)chunk*256*64;
  int g = lane >> 3, j = lane & 7;
  float acc[8] = {0.f,0.f,0.f,0.f,0.f,0.f,0.f,0.f};
  float se = 0.f;
  int tokw = w*64;
  #pragma unroll
  for (int i = 0; i < 8; ++i){
    int tok = tokw + i*8 + g;
    float e = ev[tok];
    s16x8 v8 = *reinterpret_cast<const s16x8*>(Tb + (size_t)tok*64 + j*8);
    uint4 t0 = *reinterpret_cast<const uint4*>(tabb + (size_t)tok*64 + j*8);
    uint4 t1 = *reinterpret_cast<const uint4*>(tabb + (size_t)tok*64 + j*8 + 4);
    #pragma unroll
    for (int e2 = 0; e2 < 8; ++e2){
      unsigned u = (e2 < 4) ? ((const unsigned*)&t0)[e2] : ((const unsigned*)&t1)[e2-4];
      float c  = bf2f((short)(u & 0xffff));
      float s2 = bf2f((short)(u >> 16));
      float xv = bf2f(v8[e2]);
      float xo = bf2f(v8[e2 ^ 1]);
      acc[e2] += e * (xv*c + xo*s2);
    }
    se += e;
  }
  // reduce over g (lane bits 3..5)
  #pragma unroll
  for (int m = 8; m <= 32; m <<= 1){
    #pragma unroll
    for (int e2 = 0; e2 < 8; ++e2) acc[e2] += __shfl_xor(acc[e2], m, 64);
    se += __shfl_xor(se, m, 64);
  }
  if (lane < 8){
    float4 a0 = { acc[0], acc[1], acc[2], acc[3] };
    float4 a1 = { acc[4], acc[5], acc[6], acc[7] };
    *reinterpret_cast<float4*>(&redv[w][lane*8])     = a0;
    *reinterpret_cast<float4*>(&redv[w][lane*8 + 4]) = a1;
  }
  if (lane == 0) rede[w] = se;
  __syncthreads();
  if (t < 64){
    float* ob = outp + (size_t)(bh*32 + chunk)*66;
    ob[2 + t] = redv[0][t] + redv[1][t] + redv[2][t] + redv[3][t];
    if (t == 0) ob[1] = rede[0] + rede[1] + rede[2] + rede[3];
  }
}

// ---------------- per-token epilogue: gk from partsK; u = pairsum(v*gk); r = u@w_r + b_r + q ----------------
__global__ __launch_bounds__(256) void epilogue_r(
    const __hip_bfloat16* __restrict__ vT, const __hip_bfloat16* __restrict__ qT,
    const float* __restrict__ partsK, const float* __restrict__ wr, const float* __restrict__ br,
    __hip_bfloat16* __restrict__ rb)
{
  int idx = blockIdx.x*256 + threadIdx.x;
  int bh = idx >> 13, nl = idx & 8191;
  int b = bh >> 3, h = bh & 7;
  int t = threadIdx.x;
  __shared__ float sgk[64];
  if (t < 64){
    const float* pp = partsK + (size_t)bh*32*66;
    float tot = 0.f, g = 0.f;
    #pragma unroll 4
    for (int i = 0; i < 32; ++i){ tot += pp[i*66 + 1]; g += pp[i*66 + 2 + t]; }
    sgk[t] = g / tot;
  }
  __syncthreads();

  const __hip_bfloat16* vrow = vT + (size_t)idx*64;
  const __hip_bfloat16* qrow = qT + (size_t)idx*64;
  float u[32];
  #pragma unroll
  for (int dv = 0; dv < 8; ++dv){
    s16x8 v8 = *reinterpret_cast<const s16x8*>(vrow + dv*8);
    #pragma unroll
    for (int e = 0; e < 8; e += 2){
      int d = dv*8 + e;
      u[d >> 1] = bf2f(v8[e])*sgk[d] + bf2f(v8[e+1])*sgk[d+1];
    }
  }
  __hip_bfloat16* rrow = rb + ((size_t)(b*SEQ + nl))*512 + h*64;
  #pragma unroll 2
  for (int dv = 0; dv < 8; ++dv){
    s16x8 q8 = *reinterpret_cast<const s16x8*>(qrow + dv*8);
    s16x8 o8;
    #pragma unroll
    for (int e = 0; e < 8; ++e){
      int d = dv*8 + e;
      float a2 = br[d] + bf2f(q8[e]);
      #pragma unroll
      for (int j = 0; j < 32; ++j) a2 += u[j] * wr[j*64 + d];
      o8[e] = f2bf(a2);
    }
    *reinterpret_cast<s16x8*>(rrow + dv*8) = o8;
  }
}

extern "C" void kernel_launch(void* const* d_in, const int* in_sizes, int n_in,
                              void* d_out, int out_size, void* d_ws, size_t ws_size,
                              hipStream_t stream)
{
  (void)in_sizes; (void)n_in; (void)out_size; (void)ws_size;
  const float* x    = (const float*)d_in[0];
  const float* wqkv = (const float*)d_in[1];
  const float* wql  = (const float*)d_in[2];
  const float* wkl  = (const float*)d_in[3];
  const float* wr   = (const float*)d_in[4];
  const float* br   = (const float*)d_in[5];
  const float* wout = (const float*)d_in[6];
  const float* bout = (const float*)d_in[7];
  float* out = (float*)d_out;

  char* p = (char*)d_ws;
  auto alloc = [&](size_t bytes){ char* r = p; p += (bytes + 255) & ~(size_t)255; return r; };
  __hip_bfloat16* xb    = (__hip_bfloat16*)alloc(33554432);
  __hip_bfloat16* wqkvT = (__hip_bfloat16*)alloc(1572864);
  __hip_bfloat16* woutT = (__hip_bfloat16*)alloc(524288);
  __hip_bfloat16* qT = (__hip_bfloat16*)alloc(33554432);
  __hip_bfloat16* kT = (__hip_bfloat16*)alloc(33554432);
  __hip_bfloat16* vT = (__hip_bfloat16*)alloc(33554432);
  __hip_bfloat16* rb = (__hip_bfloat16*)alloc(33554432);
  unsigned* tab = (unsigned*)alloc(2097152);   // packed bf16 cos/sin [8192][64]

  float* partsQ = (float*)xb;          // aliases xb (dead after gemm1)
  float* partsK = partsQ + 32*32*66;

  prep<<<19456, 256, 0, stream>>>(x, xb, tab, wqkv, wqkvT, wout, woutT);

  gemm128<0><<<1536, 512, 0, stream>>>(xb, wqkvT, 32768, 1536, 512,
                                       qT, kT, vT, nullptr, nullptr);

  fused_stats<0><<<dim3(32,32), 256, 0, stream>>>(qT, wql, nullptr, nullptr, tab, partsQ);
  fused_stats<1><<<dim3(32,32), 256, 0, stream>>>(kT, nullptr, partsQ, wkl, tab, partsK);

  epilogue_r<<<1024, 256, 0, stream>>>(vT, qT, partsK, wr, br, rb);

  gemm128<1><<<512, 512, 0, stream>>>(rb, woutT, 32768, 512, 512,
                                      nullptr, nullptr, nullptr, out, bout);
}